// Round 6
// baseline (179.780 us; speedup 1.0000x reference)
//
#include <hip/hip_runtime.h>

// All tensors float32. Output = concat(vec[3E], dist[E], switch[E], mask[E]).
//
// Standing model (R1/R2/R3/R4-consistent): bound by per-CU divergent-miss
// throughput, ~6.2 cyc per touched 64B line ~= 200cyc L2 latency / ~32
// outstanding L1 misses. Occupancy probe (R4) was neutral -> saturated.
// R5 probe: sc0 gathers (bypass L1, keep L2 allocation) to test whether the
// ~32-slot limiter is the L1 fill/MSHR machinery (bypassable) or the CU<->L2
// outstanding-request budget (hw floor). Value arithmetic bit-exact
// (d<5 mask cliff): fp contract OFF, numpy op order, OCML sqrtf.

typedef float f32x4 __attribute__((ext_vector_type(4)));

__device__ __forceinline__ void edge_math(
    float dx0, float dx1, float dx2,
    float sh0, float sh1, float sh2, const float c[9],
    float& v0, float& v1, float& v2, float& dist, float& sw, float& mk)
{
#pragma clang fp contract(off)
    float m0 = sh0 * c[0]; m0 = m0 + sh1 * c[3]; m0 = m0 + sh2 * c[6];
    float m1 = sh0 * c[1]; m1 = m1 + sh1 * c[4]; m1 = m1 + sh2 * c[7];
    float m2 = sh0 * c[2]; m2 = m2 + sh1 * c[5]; m2 = m2 + sh2 * c[8];
    v0 = dx0 + m0; v1 = dx1 + m1; v2 = dx2 + m2;
    float q = v0 * v0; q = q + v1 * v1; q = q + v2 * v2;
    dist = sqrtf(q);
    bool m = dist < 5.0f;
    float cv = cosf(dist * 0.62831853f);   // f32(pi/5)
    sw = m ? (0.5f * cv + 0.5f) : 0.0f;
    mk = m ? 1.0f : 0.0f;
}

// ---- prepass: coords[N,3] -> packed float4[N] in ws (16B-aligned: 1 line/node)
__global__ __launch_bounds__(256) void pack_coords_kernel(
    const float* __restrict__ coords, float4* __restrict__ packed, int n_nodes)
{
    int i = blockIdx.x * blockDim.x + threadIdx.x;
    if (i >= n_nodes) return;
    const float* p = coords + 3 * (size_t)i;
    packed[i] = make_float4(p[0], p[1], p[2], 0.0f);
}

// sc0 gather: L1 no-allocate / bypass, L2 allocate. Result NOT usable until
// the vmcnt fence below.
__device__ __forceinline__ f32x4 gather_sc0(const float4* base, int idx) {
    f32x4 r;
    const float4* p = base + idx;
    asm volatile("global_load_dwordx4 %0, %1, off sc0" : "=v"(r) : "v"(p));
    return r;
}

// ---- main kernel: 4 edges/thread, sc0 gathers ----
__global__ __launch_bounds__(256) void GraphProcessor_64012192579962_kernel(
    const float4* __restrict__ packed,  // [N] xyz_
    const int*   __restrict__ esrc,     // [E]
    const int*   __restrict__ edst,     // [E]
    const float* __restrict__ shifts,   // [E,3]
    const float* __restrict__ cells,    // [9]
    float* __restrict__ out_vec,        // [E,3]
    float* __restrict__ out_dist,       // [E]
    float* __restrict__ out_sw,         // [E]
    float* __restrict__ out_mask,       // [E]
    int n_quads, int n_edges)
{
#pragma clang fp contract(off)
    int t = blockIdx.x * blockDim.x + threadIdx.x;
    if (t >= n_quads) return;

    float c[9];
#pragma unroll
    for (int i = 0; i < 9; ++i) c[i] = cells[i];   // uniform -> scalar loads

    const int e0 = 4 * t;

    if (e0 + 3 < n_edges) {
        int4 ss = ((const int4*)esrc)[t];
        int4 dd = ((const int4*)edst)[t];
        const float4* shp = (const float4*)(shifts + 12 * (size_t)t);
        float4 h0 = shp[0], h1 = shp[1], h2 = shp[2];

        // 8 independent sc0 gathers, then one fence carrying all results
        f32x4 s0 = gather_sc0(packed, ss.x), s1 = gather_sc0(packed, ss.y);
        f32x4 s2 = gather_sc0(packed, ss.z), s3 = gather_sc0(packed, ss.w);
        f32x4 d0 = gather_sc0(packed, dd.x), d1 = gather_sc0(packed, dd.y);
        f32x4 d2 = gather_sc0(packed, dd.z), d3 = gather_sc0(packed, dd.w);
        asm volatile("s_waitcnt vmcnt(0)"
                     : "+v"(s0), "+v"(s1), "+v"(s2), "+v"(s3),
                       "+v"(d0), "+v"(d1), "+v"(d2), "+v"(d3));

        float v[12], di[4], sw[4], mk[4];
        edge_math(d0.x - s0.x, d0.y - s0.y, d0.z - s0.z, h0.x, h0.y, h0.z, c, v[0], v[1],  v[2],  di[0], sw[0], mk[0]);
        edge_math(d1.x - s1.x, d1.y - s1.y, d1.z - s1.z, h0.w, h1.x, h1.y, c, v[3], v[4],  v[5],  di[1], sw[1], mk[1]);
        edge_math(d2.x - s2.x, d2.y - s2.y, d2.z - s2.z, h1.z, h1.w, h2.x, c, v[6], v[7],  v[8],  di[2], sw[2], mk[2]);
        edge_math(d3.x - s3.x, d3.y - s3.y, d3.z - s3.z, h2.y, h2.z, h2.w, c, v[9], v[10], v[11], di[3], sw[3], mk[3]);

        float4* ov = (float4*)(out_vec + 12 * (size_t)t);
        ov[0] = make_float4(v[0], v[1], v[2],  v[3]);
        ov[1] = make_float4(v[4], v[5], v[6],  v[7]);
        ov[2] = make_float4(v[8], v[9], v[10], v[11]);
        ((float4*)out_dist)[t] = make_float4(di[0], di[1], di[2], di[3]);
        ((float4*)out_sw)[t]   = make_float4(sw[0], sw[1], sw[2], sw[3]);
        ((float4*)out_mask)[t] = make_float4(mk[0], mk[1], mk[2], mk[3]);
    } else {
        for (int e = e0; e < n_edges; ++e) {
            float4 s = packed[esrc[e]], d = packed[edst[e]];
            float v0, v1, v2, di, sw, mk;
            edge_math(d.x - s.x, d.y - s.y, d.z - s.z,
                      shifts[3 * (size_t)e], shifts[3 * (size_t)e + 1],
                      shifts[3 * (size_t)e + 2], c, v0, v1, v2, di, sw, mk);
            out_vec[3 * (size_t)e]     = v0;
            out_vec[3 * (size_t)e + 1] = v1;
            out_vec[3 * (size_t)e + 2] = v2;
            out_dist[e] = di;
            out_sw[e]   = sw;
            out_mask[e] = mk;
        }
    }
}

// ---- fallback (ws too small): 12B struct gathers straight from coords ----
struct F3 { float x, y, z; };

__global__ __launch_bounds__(256) void GraphProcessor_fallback_kernel(
    const float* __restrict__ coords,
    const int*   __restrict__ esrc,
    const int*   __restrict__ edst,
    const float* __restrict__ shifts,
    const float* __restrict__ cells,
    float* __restrict__ out_vec,
    float* __restrict__ out_dist,
    float* __restrict__ out_sw,
    float* __restrict__ out_mask,
    int n_pairs, int n_edges)
{
#pragma clang fp contract(off)
    int t = blockIdx.x * blockDim.x + threadIdx.x;
    if (t >= n_pairs) return;

    float c[9];
#pragma unroll
    for (int i = 0; i < 9; ++i) c[i] = cells[i];

    const F3* nodes = (const F3*)coords;

    for (int e = 2 * t; e < n_edges && e < 2 * t + 2; ++e) {
        F3 s = nodes[esrc[e]], d = nodes[edst[e]];
        float v0, v1, v2, di, sw, mk;
        edge_math(d.x - s.x, d.y - s.y, d.z - s.z,
                  shifts[3 * (size_t)e], shifts[3 * (size_t)e + 1],
                  shifts[3 * (size_t)e + 2], c, v0, v1, v2, di, sw, mk);
        out_vec[3 * (size_t)e]     = v0;
        out_vec[3 * (size_t)e + 1] = v1;
        out_vec[3 * (size_t)e + 2] = v2;
        out_dist[e] = di;
        out_sw[e]   = sw;
        out_mask[e] = mk;
    }
}

extern "C" void kernel_launch(void* const* d_in, const int* in_sizes, int n_in,
                              void* d_out, int out_size, void* d_ws, size_t ws_size,
                              hipStream_t stream) {
    const float* coords = (const float*)d_in[0];
    const int*   esrc   = (const int*)d_in[1];
    const int*   edst   = (const int*)d_in[2];
    const float* shifts = (const float*)d_in[3];
    const float* cells  = (const float*)d_in[4];

    const int N = in_sizes[0] / 3;  // n_nodes
    const int E = in_sizes[1];      // n_edges

    float* out      = (float*)d_out;
    float* out_vec  = out;                     // [E,3]
    float* out_dist = out + 3 * (size_t)E;     // [E]
    float* out_sw   = out_dist + E;            // [E]
    float* out_mask = out_sw + E;              // [E]

    if (ws_size >= (size_t)N * sizeof(float4)) {
        float4* packed = (float4*)d_ws;
        pack_coords_kernel<<<(N + 255) / 256, 256, 0, stream>>>(coords, packed, N);
        const int n_quads = (E + 3) / 4;
        dim3 grid((n_quads + 255) / 256);
        GraphProcessor_64012192579962_kernel<<<grid, dim3(256), 0, stream>>>(
            packed, esrc, edst, shifts, cells,
            out_vec, out_dist, out_sw, out_mask, n_quads, E);
    } else {
        const int n_pairs = (E + 1) / 2;
        dim3 grid((n_pairs + 255) / 256);
        GraphProcessor_fallback_kernel<<<grid, dim3(256), 0, stream>>>(
            coords, esrc, edst, shifts, cells,
            out_vec, out_dist, out_sw, out_mask, n_pairs, E);
    }
}

// Round 7
// 172.248 us; speedup vs baseline: 1.0437x; 1.0437x over previous
//
#include <hip/hip_runtime.h>

// All tensors float32. Output = concat(vec[3E], dist[E], switch[E], mask[E]).
//
// FINAL (R6 = revert to R4 structure, the measured best at 68-70us).
//
// Bottleneck model, confirmed by 5 probes (R1-R5): per-CU divergent-miss
// throughput, ~6.2 cyc per touched 64B line (~25K lines/CU => ~65us floor).
//   R2 (3x fewer gather instrs)     -> neutral: cost unit is the touched line
//   R3 (nt loads, 16-deep MLP)      -> 2x regress: nt kills L2 residency
//   R4 (2x waves, occupancy 55->65) -> neutral: miss pipe saturated
//   R5 (sc0 L1-bypass)              -> 10% regress: L1 filters re-touches;
//                                      limiter is the CU<->L2 request pipe
// Structural floor: output is edge-ordered, endpoints random => 2 divergent
// line-touches/edge is minimal (sort/bucket pays >=2 extra on permute-back).
//
// Numerics: d<5 mask is a bit-exact cliff -> fp contract OFF, numpy op
// order, OCML sqrtf. Accurate cosf (VALU is ~8% busy; it's free).

__device__ __forceinline__ void edge_math(
    float dx0, float dx1, float dx2,
    float sh0, float sh1, float sh2, const float c[9],
    float& v0, float& v1, float& v2, float& dist, float& sw, float& mk)
{
#pragma clang fp contract(off)
    float m0 = sh0 * c[0]; m0 = m0 + sh1 * c[3]; m0 = m0 + sh2 * c[6];
    float m1 = sh0 * c[1]; m1 = m1 + sh1 * c[4]; m1 = m1 + sh2 * c[7];
    float m2 = sh0 * c[2]; m2 = m2 + sh1 * c[5]; m2 = m2 + sh2 * c[8];
    v0 = dx0 + m0; v1 = dx1 + m1; v2 = dx2 + m2;
    float q = v0 * v0; q = q + v1 * v1; q = q + v2 * v2;
    dist = sqrtf(q);
    bool m = dist < 5.0f;
    float cv = cosf(dist * 0.62831853f);   // f32(pi/5)
    sw = m ? (0.5f * cv + 0.5f) : 0.0f;
    mk = m ? 1.0f : 0.0f;
}

// ---- prepass: coords[N,3] -> packed float4[N] in ws (16B-aligned: 1 line/node)
__global__ __launch_bounds__(256) void pack_coords_kernel(
    const float* __restrict__ coords, float4* __restrict__ packed, int n_nodes)
{
    int i = blockIdx.x * blockDim.x + threadIdx.x;
    if (i >= n_nodes) return;
    const float* p = coords + 3 * (size_t)i;
    packed[i] = make_float4(p[0], p[1], p[2], 0.0f);
}

// ---- main kernel: 2 edges/thread, cached gathers, coalesced stores ----
__global__ __launch_bounds__(256) void GraphProcessor_64012192579962_kernel(
    const float4* __restrict__ packed,  // [N] xyz_
    const int*   __restrict__ esrc,     // [E]
    const int*   __restrict__ edst,     // [E]
    const float* __restrict__ shifts,   // [E,3]
    const float* __restrict__ cells,    // [9]
    float* __restrict__ out_vec,        // [E,3]
    float* __restrict__ out_dist,       // [E]
    float* __restrict__ out_sw,         // [E]
    float* __restrict__ out_mask,       // [E]
    int n_pairs, int n_edges)
{
#pragma clang fp contract(off)
    int t = blockIdx.x * blockDim.x + threadIdx.x;
    if (t >= n_pairs) return;

    float c[9];
#pragma unroll
    for (int i = 0; i < 9; ++i) c[i] = cells[i];   // uniform -> scalar loads

    const int e0 = 2 * t;

    if (e0 + 1 < n_edges) {
        int2 ss = ((const int2*)esrc)[t];
        int2 dd = ((const int2*)edst)[t];
        const float2* shp = (const float2*)(shifts + 6 * (size_t)t);  // 24B @ 8B align
        float2 g0 = shp[0], g1 = shp[1], g2 = shp[2];

        // 4 independent gathers issued before any compute
        float4 s0 = packed[ss.x], s1 = packed[ss.y];
        float4 d0 = packed[dd.x], d1 = packed[dd.y];

        float vA0, vA1, vA2, diA, swA, mkA;
        float vB0, vB1, vB2, diB, swB, mkB;
        edge_math(d0.x - s0.x, d0.y - s0.y, d0.z - s0.z, g0.x, g0.y, g1.x, c,
                  vA0, vA1, vA2, diA, swA, mkA);
        edge_math(d1.x - s1.x, d1.y - s1.y, d1.z - s1.z, g1.y, g2.x, g2.y, c,
                  vB0, vB1, vB2, diB, swB, mkB);

        float2* ov = (float2*)(out_vec + 6 * (size_t)t);  // 24B @ 8B align
        ov[0] = make_float2(vA0, vA1);
        ov[1] = make_float2(vA2, vB0);
        ov[2] = make_float2(vB1, vB2);
        ((float2*)out_dist)[t] = make_float2(diA, diB);
        ((float2*)out_sw)[t]   = make_float2(swA, swB);
        ((float2*)out_mask)[t] = make_float2(mkA, mkB);
    } else {
        for (int e = e0; e < n_edges; ++e) {
            float4 s = packed[esrc[e]], d = packed[edst[e]];
            float v0, v1, v2, di, sw, mk;
            edge_math(d.x - s.x, d.y - s.y, d.z - s.z,
                      shifts[3 * (size_t)e], shifts[3 * (size_t)e + 1],
                      shifts[3 * (size_t)e + 2], c, v0, v1, v2, di, sw, mk);
            out_vec[3 * (size_t)e]     = v0;
            out_vec[3 * (size_t)e + 1] = v1;
            out_vec[3 * (size_t)e + 2] = v2;
            out_dist[e] = di;
            out_sw[e]   = sw;
            out_mask[e] = mk;
        }
    }
}

// ---- fallback (ws too small): 12B struct gathers straight from coords ----
struct F3 { float x, y, z; };

__global__ __launch_bounds__(256) void GraphProcessor_fallback_kernel(
    const float* __restrict__ coords,
    const int*   __restrict__ esrc,
    const int*   __restrict__ edst,
    const float* __restrict__ shifts,
    const float* __restrict__ cells,
    float* __restrict__ out_vec,
    float* __restrict__ out_dist,
    float* __restrict__ out_sw,
    float* __restrict__ out_mask,
    int n_pairs, int n_edges)
{
#pragma clang fp contract(off)
    int t = blockIdx.x * blockDim.x + threadIdx.x;
    if (t >= n_pairs) return;

    float c[9];
#pragma unroll
    for (int i = 0; i < 9; ++i) c[i] = cells[i];

    const F3* nodes = (const F3*)coords;

    for (int e = 2 * t; e < n_edges && e < 2 * t + 2; ++e) {
        F3 s = nodes[esrc[e]], d = nodes[edst[e]];
        float v0, v1, v2, di, sw, mk;
        edge_math(d.x - s.x, d.y - s.y, d.z - s.z,
                  shifts[3 * (size_t)e], shifts[3 * (size_t)e + 1],
                  shifts[3 * (size_t)e + 2], c, v0, v1, v2, di, sw, mk);
        out_vec[3 * (size_t)e]     = v0;
        out_vec[3 * (size_t)e + 1] = v1;
        out_vec[3 * (size_t)e + 2] = v2;
        out_dist[e] = di;
        out_sw[e]   = sw;
        out_mask[e] = mk;
    }
}

extern "C" void kernel_launch(void* const* d_in, const int* in_sizes, int n_in,
                              void* d_out, int out_size, void* d_ws, size_t ws_size,
                              hipStream_t stream) {
    const float* coords = (const float*)d_in[0];
    const int*   esrc   = (const int*)d_in[1];
    const int*   edst   = (const int*)d_in[2];
    const float* shifts = (const float*)d_in[3];
    const float* cells  = (const float*)d_in[4];

    const int N = in_sizes[0] / 3;  // n_nodes
    const int E = in_sizes[1];      // n_edges

    float* out      = (float*)d_out;
    float* out_vec  = out;                     // [E,3]
    float* out_dist = out + 3 * (size_t)E;     // [E]
    float* out_sw   = out_dist + E;            // [E]
    float* out_mask = out_sw + E;              // [E]

    const int n_pairs = (E + 1) / 2;
    dim3 grid((n_pairs + 255) / 256);

    if (ws_size >= (size_t)N * sizeof(float4)) {
        float4* packed = (float4*)d_ws;
        pack_coords_kernel<<<(N + 255) / 256, 256, 0, stream>>>(coords, packed, N);
        GraphProcessor_64012192579962_kernel<<<grid, dim3(256), 0, stream>>>(
            packed, esrc, edst, shifts, cells,
            out_vec, out_dist, out_sw, out_mask, n_pairs, E);
    } else {
        GraphProcessor_fallback_kernel<<<grid, dim3(256), 0, stream>>>(
            coords, esrc, edst, shifts, cells,
            out_vec, out_dist, out_sw, out_mask, n_pairs, E);
    }
}